// Round 6
// baseline (522.107 us; speedup 1.0000x reference)
//
#include <hip/hip_runtime.h>
#include <hip/hip_bf16.h>
#include <math.h>

typedef unsigned short u16;
typedef unsigned int u32;
using short8 = __attribute__((ext_vector_type(8))) short;
using f32x4  = __attribute__((ext_vector_type(4))) float;

// ---------- bf16 helpers ----------
__device__ __forceinline__ float bf2f(u16 h) {
  union { float f; u32 u; } c; c.u = ((u32)h) << 16; return c.f;
}
__device__ __forceinline__ u16 f2bf(float f) {
  union { float f; u32 u; } c; c.f = f;
  u32 u = c.u;
  u += 0x7FFFu + ((u >> 16) & 1u);   // RNE (finite inputs only)
  return (u16)(u >> 16);
}
__device__ __forceinline__ u32 pack2(float a, float b) {
  return (u32)f2bf(a) | ((u32)f2bf(b) << 16);
}

// ---------- async global->LDS, 16B per lane (dest = wave-uniform base + lane*16)
__device__ __forceinline__ void gl2lds16(const u16* g, u16* l) {
  __builtin_amdgcn_global_load_lds(
      (const __attribute__((address_space(1))) void*)g,
      (__attribute__((address_space(3))) void*)l, 16, 0, 0);
}

// ---------- NT bf16 GEMM core (m97 structure, single-buffer — R2 proven) ----------
// C(128x128) = A[MxK] * B[NxK]^T. A,B offset to tile start; row stride = K.
// acc[i][j][r]: row m = wm + i*16 + (lane>>4)*4 + r ; col n = wn + j*16 + (lane&15)
#define BK 32
__device__ __forceinline__ void gemm_tile(const u16* __restrict__ A,
                                          const u16* __restrict__ B,
                                          int K, f32x4 acc[4][4]) {
  __shared__ u16 As[128 * BK];
  __shared__ u16 Bs[128 * BK];
  const int tid  = threadIdx.x;
  const int lane = tid & 63;
  const int wave = tid >> 6;
  const int wm = (wave >> 1) * 64;
  const int wn = (wave & 1) * 64;
  const int qd  = lane >> 4;
  const int l15 = lane & 15;

#pragma unroll
  for (int i = 0; i < 4; ++i)
#pragma unroll
    for (int j = 0; j < 4; ++j)
      acc[i][j] = (f32x4){0.f, 0.f, 0.f, 0.f};

  const int r0 = wave * 16 + (lane >> 2);
  const int c0 = (lane & 3) * 8;
  const u16* pa0 = A + (size_t)r0 * K + c0;
  const u16* pb0 = B + (size_t)r0 * K + c0;
  const u16* pa1 = pa0 + (size_t)64 * K;
  const u16* pb1 = pb0 + (size_t)64 * K;
  u16* la0 = As + wave * 512;
  u16* la1 = As + (4 + wave) * 512;
  u16* lb0 = Bs + wave * 512;
  u16* lb1 = Bs + (4 + wave) * 512;

  for (int k0 = 0; k0 < K; k0 += BK) {
    gl2lds16(pa0, la0);
    gl2lds16(pa1, la1);
    gl2lds16(pb0, lb0);
    gl2lds16(pb1, lb1);
    pa0 += BK; pa1 += BK; pb0 += BK; pb1 += BK;
    __syncthreads();
    short8 af[4], bfr[4];
#pragma unroll
    for (int i = 0; i < 4; ++i)
      af[i] = *(const short8*)&As[(wm + i * 16 + l15) * BK + qd * 8];
#pragma unroll
    for (int j = 0; j < 4; ++j)
      bfr[j] = *(const short8*)&Bs[(wn + j * 16 + l15) * BK + qd * 8];
#pragma unroll
    for (int i = 0; i < 4; ++i)
#pragma unroll
      for (int j = 0; j < 4; ++j)
        acc[i][j] = __builtin_amdgcn_mfma_f32_16x16x32_bf16(af[i], bfr[j], acc[i][j], 0, 0, 0);
    __syncthreads();
  }
}

// ---------- qk-local variant: same core, LDS passed in (so qk can reuse it) ----
__device__ __forceinline__ void gemm_tile_sh(const u16* __restrict__ A,
                                             const u16* __restrict__ B,
                                             int K, f32x4 acc[4][4],
                                             u16* As, u16* Bs) {
  const int tid  = threadIdx.x;
  const int lane = tid & 63;
  const int wave = tid >> 6;
  const int wm = (wave >> 1) * 64;
  const int wn = (wave & 1) * 64;
  const int qd  = lane >> 4;
  const int l15 = lane & 15;

#pragma unroll
  for (int i = 0; i < 4; ++i)
#pragma unroll
    for (int j = 0; j < 4; ++j)
      acc[i][j] = (f32x4){0.f, 0.f, 0.f, 0.f};

  const int r0 = wave * 16 + (lane >> 2);
  const int c0 = (lane & 3) * 8;
  const u16* pa0 = A + (size_t)r0 * K + c0;
  const u16* pb0 = B + (size_t)r0 * K + c0;
  const u16* pa1 = pa0 + (size_t)64 * K;
  const u16* pb1 = pb0 + (size_t)64 * K;
  u16* la0 = As + wave * 512;
  u16* la1 = As + (4 + wave) * 512;
  u16* lb0 = Bs + wave * 512;
  u16* lb1 = Bs + (4 + wave) * 512;

  for (int k0 = 0; k0 < K; k0 += BK) {
    gl2lds16(pa0, la0);
    gl2lds16(pa1, la1);
    gl2lds16(pb0, lb0);
    gl2lds16(pb1, lb1);
    pa0 += BK; pa1 += BK; pb0 += BK; pb1 += BK;
    __syncthreads();
    short8 af[4], bfr[4];
#pragma unroll
    for (int i = 0; i < 4; ++i)
      af[i] = *(const short8*)&As[(wm + i * 16 + l15) * BK + qd * 8];
#pragma unroll
    for (int j = 0; j < 4; ++j)
      bfr[j] = *(const short8*)&Bs[(wn + j * 16 + l15) * BK + qd * 8];
#pragma unroll
    for (int i = 0; i < 4; ++i)
#pragma unroll
      for (int j = 0; j < 4; ++j)
        acc[i][j] = __builtin_amdgcn_mfma_f32_16x16x32_bf16(af[i], bfr[j], acc[i][j], 0, 0, 0);
    __syncthreads();
  }
}

// ---------- BK=64 twin-tile variant (for pv, K=2048): halves barrier/drain count --
__device__ __forceinline__ void gemm_tile_bk64(const u16* __restrict__ A,
                                               const u16* __restrict__ B,
                                               int K, f32x4 acc[4][4]) {
  __shared__ u16 As[2][128 * 32];
  __shared__ u16 Bs[2][128 * 32];
  const int tid  = threadIdx.x;
  const int lane = tid & 63;
  const int wave = tid >> 6;
  const int wm = (wave >> 1) * 64;
  const int wn = (wave & 1) * 64;
  const int qd  = lane >> 4;
  const int l15 = lane & 15;

#pragma unroll
  for (int i = 0; i < 4; ++i)
#pragma unroll
    for (int j = 0; j < 4; ++j)
      acc[i][j] = (f32x4){0.f, 0.f, 0.f, 0.f};

  const int r0 = wave * 16 + (lane >> 2);
  const int c0 = (lane & 3) * 8;
  const u16* pa0 = A + (size_t)r0 * K + c0;
  const u16* pb0 = B + (size_t)r0 * K + c0;
  const u16* pa1 = pa0 + (size_t)64 * K;
  const u16* pb1 = pb0 + (size_t)64 * K;
  const int lo0 = wave * 512;
  const int lo1 = (4 + wave) * 512;

  for (int k0 = 0; k0 < K; k0 += 64) {
    gl2lds16(pa0,      &As[0][lo0]);
    gl2lds16(pa1,      &As[0][lo1]);
    gl2lds16(pb0,      &Bs[0][lo0]);
    gl2lds16(pb1,      &Bs[0][lo1]);
    gl2lds16(pa0 + 32, &As[1][lo0]);
    gl2lds16(pa1 + 32, &As[1][lo1]);
    gl2lds16(pb0 + 32, &Bs[1][lo0]);
    gl2lds16(pb1 + 32, &Bs[1][lo1]);
    pa0 += 64; pa1 += 64; pb0 += 64; pb1 += 64;
    __syncthreads();
#pragma unroll
    for (int h = 0; h < 2; ++h) {
      short8 af[4], bfr[4];
#pragma unroll
      for (int i = 0; i < 4; ++i)
        af[i] = *(const short8*)&As[h][(wm + i * 16 + l15) * 32 + qd * 8];
#pragma unroll
      for (int j = 0; j < 4; ++j)
        bfr[j] = *(const short8*)&Bs[h][(wn + j * 16 + l15) * 32 + qd * 8];
#pragma unroll
      for (int i = 0; i < 4; ++i)
#pragma unroll
        for (int j = 0; j < 4; ++j)
          acc[i][j] = __builtin_amdgcn_mfma_f32_16x16x32_bf16(af[i], bfr[j], acc[i][j], 0, 0, 0);
    }
    __syncthreads();
  }
}

// ---------- converts ----------
__global__ void __launch_bounds__(256) cvt_kernel(const float* __restrict__ in,
                                                  u16* __restrict__ out, int n8) {
  int i = blockIdx.x * 256 + threadIdx.x;
  if (i >= n8) return;
  const float4* f = (const float4*)in + (size_t)i * 2;
  float4 f0 = f[0], f1 = f[1];
  uint4 u;
  u.x = pack2(f0.x, f0.y); u.y = pack2(f0.z, f0.w);
  u.z = pack2(f1.x, f1.y); u.w = pack2(f1.z, f1.w);
  *(uint4*)(out + (size_t)i * 8) = u;
}

struct CvtWArgs { const float* w[8]; };
__global__ void __launch_bounds__(256) cvt_w_kernel(CvtWArgs a, u16* __restrict__ out) {
  const int z = blockIdx.z;
  const int i = blockIdx.x * 256 + threadIdx.x;
  const float4* f = (const float4*)(a.w[z]) + (size_t)i * 2;
  float4 f0 = f[0], f1 = f[1];
  uint4 u;
  u.x = pack2(f0.x, f0.y); u.y = pack2(f0.z, f0.w);
  u.z = pack2(f1.x, f1.y); u.w = pack2(f1.z, f1.w);
  *(uint4*)(out + (size_t)z * 262144 + (size_t)i * 8) = u;
}

// ---------- zero RS ----------
__global__ void __launch_bounds__(256) zero_kernel(float* __restrict__ p, int n4) {
  int i = blockIdx.x * 256 + threadIdx.x;
  if (i < n4) ((float4*)p)[i] = (float4){0.f, 0.f, 0.f, 0.f};
}

// ---------- projections: q,k,g: out = X W^T + b (bf16). v: out = (X Wv^T + b)^T ----
struct ProjArgs {
  const u16* X[4];
  const u16* W[4];
  const float* bias[4];
  u16* out[4];
};
__global__ void __launch_bounds__(256) proj_kernel(ProjArgs args) {
  const u32 wg = blockIdx.x;
  const int n = wg >> 9;            // 0..3
  const int m = (wg >> 2) & 127;    // 0..127
  const int idx = wg & 3;           // 0..3 (q,k,v,g)
  f32x4 acc[4][4];
  const u16* Aop = (idx == 2) ? args.W[2] + (size_t)(n * 128) * 512
                              : args.X[idx] + (size_t)(m * 128) * 512;
  const u16* Bop = (idx == 2) ? args.X[2] + (size_t)(m * 128) * 512
                              : args.W[idx] + (size_t)(n * 128) * 512;
  gemm_tile(Aop, Bop, 512, acc);
  const int lane = threadIdx.x & 63, wave = threadIdx.x >> 6;
  const int wm = (wave >> 1) * 64, wn = (wave & 1) * 64;
  const int qd = lane >> 4, l15 = lane & 15;
  const float* bias = args.bias[idx];
  u16* outp = args.out[idx];
  if (idx == 2) {
    // rows = d in [0,512), cols = k in [0,16384); Vt[b][d][kc], b=k>>11, kc=k&2047
    const int dRow0 = n * 128;
    const int kCol0 = m * 128;
#pragma unroll
    for (int j = 0; j < 4; ++j) {
      const int gk = kCol0 + wn + j * 16 + l15;
      const int bb = gk >> 11, kc = gk & 2047;
      u16* dcol = outp + (size_t)bb * (512 * 2048) + kc;
#pragma unroll
      for (int i = 0; i < 4; ++i) {
        const int gd0 = dRow0 + wm + i * 16 + qd * 4;
#pragma unroll
        for (int r = 0; r < 4; ++r)
          dcol[(size_t)(gd0 + r) * 2048] = f2bf(acc[i][j][r] + bias[gd0 + r]);
      }
    }
  } else {
    const int tileN = n * 128;
    const int tileM = m * 128;
#pragma unroll
    for (int j = 0; j < 4; ++j) {
      const int gn = tileN + wn + j * 16 + l15;
      const float bj = bias[gn];
#pragma unroll
      for (int i = 0; i < 4; ++i) {
        const int gm = tileM + wm + i * 16 + qd * 4;
#pragma unroll
        for (int r = 0; r < 4; ++r)
          outp[(size_t)(gm + r) * 512 + gn] = f2bf(acc[i][j][r] + bj);
      }
    }
  }
}

// ---------- P' = exp(scale * Q K^T) (8 batches), bf16 out, no max-subtract ----
// Epilogue: C-tile staged through LDS (reusing the 16KB GEMM buffers) in 4 passes
// of 32 rows -> fully coalesced 32B/lane vector stores (kills 1.77x write amp).
// Rowsum folded into the readback (16-col partial + 3 shfl + 1 atomic per row).
__global__ void __launch_bounds__(256) qk_kernel(const u16* __restrict__ Q,
                                                 const u16* __restrict__ Kmat,
                                                 u16* __restrict__ S,
                                                 float* __restrict__ RS) {
  __shared__ u16 sh[2][128 * BK];          // GEMM staging, then f32 C-scratch
  const u32 wg = blockIdx.x;
  const int n = wg >> 7;            // 0..15
  const int m = (wg >> 3) & 15;     // 0..15
  const int b = wg & 7;             // 0..7
  const int tileN = n * 128;
  const int tileM = m * 128;
  f32x4 acc[4][4];
  gemm_tile_sh(Q + (size_t)b * 2048 * 512 + (size_t)tileM * 512,
               Kmat + (size_t)b * 2048 * 512 + (size_t)tileN * 512, 512, acc,
               sh[0], sh[1]);
  const int tid = threadIdx.x;
  const int lane = tid & 63, wave = tid >> 6;
  const int wm = (wave >> 1) * 64, wn = (wave & 1) * 64;
  const int qd = lane >> 4, l15 = lane & 15;
  u16* Sp = S + (size_t)b * 2048 * 2048;
  float* RSb = RS + (size_t)b * 2048;
  const float scale = 0.04419417382415922f;  // 1/sqrt(512)
  float* scr = (float*)sh;                   // 4096 f32 = 32 rows x 128 cols

#pragma unroll
  for (int p = 0; p < 4; ++p) {
    // scatter this pass's 32 rows (global rows tileM+32p .. +31) into scratch
    if ((wm >> 6) == (p >> 1)) {
#pragma unroll
      for (int ii = 0; ii < 2; ++ii) {
        const int i = 2 * (p & 1) + ii;
#pragma unroll
        for (int j = 0; j < 4; ++j) {
          const int col = wn + j * 16 + l15;
#pragma unroll
          for (int r = 0; r < 4; ++r)
            scr[(ii * 16 + qd * 4 + r) * 128 + col] = acc[i][j][r];
        }
      }
    }
    __syncthreads();
    // contiguous readback: 16 f32/thread -> exp -> 16 bf16 -> 2 x uint4 store
    const float4* sp = (const float4*)(scr + (size_t)tid * 16);
    float e[16];
#pragma unroll
    for (int k = 0; k < 4; ++k) {
      float4 v = sp[k];
      e[k * 4 + 0] = __expf(v.x * scale);
      e[k * 4 + 1] = __expf(v.y * scale);
      e[k * 4 + 2] = __expf(v.z * scale);
      e[k * 4 + 3] = __expf(v.w * scale);
    }
    const int grow = tileM + 32 * p + (tid >> 3);
    const int gcol = tileN + (tid & 7) * 16;
    uint4 s0, s1;
    s0.x = pack2(e[0], e[1]);  s0.y = pack2(e[2], e[3]);
    s0.z = pack2(e[4], e[5]);  s0.w = pack2(e[6], e[7]);
    s1.x = pack2(e[8], e[9]);  s1.y = pack2(e[10], e[11]);
    s1.z = pack2(e[12], e[13]); s1.w = pack2(e[14], e[15]);
    u16* dst = Sp + (size_t)grow * 2048 + gcol;
    *(uint4*)dst = s0;
    *(uint4*)(dst + 8) = s1;
    float rs = 0.f;
#pragma unroll
    for (int k = 0; k < 16; ++k) rs += e[k];
    rs += __shfl_xor(rs, 1);
    rs += __shfl_xor(rs, 2);
    rs += __shfl_xor(rs, 4);
    if ((tid & 7) == 0) atomicAdd(&RSb[grow], rs);
    __syncthreads();   // scratch reused next pass
  }
}

// ---------- O = P' V ; out = hq + sigmoid(g) * O / RS[row] ----------
// 128x128 tiles, BK=64 twin-tile core: 32 barrier/drain exposures instead of 64.
__global__ void __launch_bounds__(256) pv_kernel(const u16* __restrict__ P,
                                                 const u16* __restrict__ Vt,
                                                 const float* __restrict__ hq,
                                                 const u16* __restrict__ gate,
                                                 const float* __restrict__ RS,
                                                 float* __restrict__ outp) {
  const u32 wg = blockIdx.x;
  const int n = wg >> 7;            // 0..3
  const int m = (wg >> 3) & 15;     // 0..15
  const int b = wg & 7;             // 0..7
  const int tileN = n * 128;
  const int tileM = m * 128;
  f32x4 acc[4][4];
  gemm_tile_bk64(P + (size_t)b * 2048 * 2048 + (size_t)tileM * 2048,
                 Vt + (size_t)b * 512 * 2048 + (size_t)tileN * 2048, 2048, acc);
  const int lane = threadIdx.x & 63, wave = threadIdx.x >> 6;
  const int wm = (wave >> 1) * 64, wn = (wave & 1) * 64;
  const int qd = lane >> 4, l15 = lane & 15;
  float invr[4][4];
#pragma unroll
  for (int i = 0; i < 4; ++i) {
    const int lm = wm + i * 16 + qd * 4;
#pragma unroll
    for (int r = 0; r < 4; ++r)
      invr[i][r] = 1.f / RS[(size_t)b * 2048 + tileM + lm + r];
  }
#pragma unroll
  for (int j = 0; j < 4; ++j) {
    const int gn = tileN + wn + j * 16 + l15;
#pragma unroll
    for (int i = 0; i < 4; ++i) {
      const int lm = wm + i * 16 + qd * 4;
#pragma unroll
      for (int r = 0; r < 4; ++r) {
        const size_t o = (size_t)(b * 2048 + tileM + lm + r) * 512 + gn;
        const float gv = bf2f(gate[o]);
        outp[o] = hq[o] + (acc[i][j][r] * invr[i][r]) / (1.f + __expf(-gv));
      }
    }
  }
}

extern "C" void kernel_launch(void* const* d_in, const int* in_sizes, int n_in,
                              void* d_out, int out_size, void* d_ws, size_t ws_size,
                              hipStream_t stream) {
  const size_t NX = (size_t)16384 * 512;   // per-direction tensor elems (B*L*D)
  // ws layout (u16 elems): ~172 MB total
  u16* Xb = (u16*)d_ws;                    // [2][16384][512] bf16 h_s, h_c
  u16* Wb = Xb + 2 * NX;                   // [8][512][512]
  u16* Qd = Wb + (size_t)8 * 262144;       // per-dir [8][2048][512]
  u16* Kd = Qd + NX;
  u16* Vt = Kd + NX;                       // per-dir [8][512][2048] (direct-transposed V)
  u16* Gd = Vt + NX;
  u16* Sd = Gd + NX;                       // per-dir [8][2048][2048] (P' = exp)
  float* RS = (float*)(Sd + 4 * NX);       // [2][8][2048] f32 rowsums

  // converts (once)
  cvt_kernel<<<dim3((u32)(NX / 2048)), 256, 0, stream>>>((const float*)d_in[0], Xb, (int)(NX / 8));
  cvt_kernel<<<dim3((u32)(NX / 2048)), 256, 0, stream>>>((const float*)d_in[1], Xb + NX, (int)(NX / 8));
  // Wb slot order: qs,kc,vc,gs | qc,ks,vs,gc
  static const int wsrc[8] = {2, 4, 6, 14, 8, 10, 12, 16};
  CvtWArgs wa;
  for (int i = 0; i < 8; ++i) wa.w[i] = (const float*)d_in[wsrc[i]];
  cvt_w_kernel<<<dim3(128, 1, 8), 256, 0, stream>>>(wa, Wb);
  zero_kernel<<<dim3(32), 256, 0, stream>>>(RS, 8192);   // 2*8*2048 f32 = 8192 float4

  for (int dir = 0; dir < 2; ++dir) {
    const u16* Xq  = dir ? Xb + NX : Xb;   // h_q source (h_s for dir0, h_c for dir1)
    const u16* Xkv = dir ? Xb : Xb + NX;
    static const int wslot[2][4] = {{0, 1, 2, 3}, {4, 5, 6, 7}};
    static const int bidx[2][4]  = {{3, 5, 7, 15}, {9, 11, 13, 17}};
    const u16* xin[4] = {Xq, Xkv, Xkv, Xq};
    u16* outs[4] = {Qd, Kd, Vt, Gd};
    ProjArgs pa;
    for (int i = 0; i < 4; ++i) {
      pa.X[i] = xin[i];
      pa.W[i] = Wb + (size_t)262144 * wslot[dir][i];
      pa.bias[i] = (const float*)d_in[bidx[dir][i]];
      pa.out[i] = outs[i];
    }
    proj_kernel<<<dim3(2048), 256, 0, stream>>>(pa);

    float* RSd = RS + (size_t)dir * 16384;
    qk_kernel<<<dim3(2048), 256, 0, stream>>>(Qd, Kd, Sd, RSd);
    pv_kernel<<<dim3(512), 256, 0, stream>>>(
        Sd, Vt, (const float*)d_in[dir], Gd, RSd, (float*)d_out + dir * NX);
  }
}

// Round 8
// 467.528 us; speedup vs baseline: 1.1167x; 1.1167x over previous
//
#include <hip/hip_runtime.h>
#include <hip/hip_bf16.h>
#include <math.h>

typedef unsigned short u16;
typedef unsigned int u32;
using short8 = __attribute__((ext_vector_type(8))) short;
using f32x4  = __attribute__((ext_vector_type(4))) float;

// ---------- bf16 helpers ----------
__device__ __forceinline__ float bf2f(u16 h) {
  union { float f; u32 u; } c; c.u = ((u32)h) << 16; return c.f;
}
__device__ __forceinline__ u16 f2bf(float f) {
  union { float f; u32 u; } c; c.f = f;
  u32 u = c.u;
  u += 0x7FFFu + ((u >> 16) & 1u);   // RNE (finite inputs only)
  return (u16)(u >> 16);
}
__device__ __forceinline__ u32 pack2(float a, float b) {
  return (u32)f2bf(a) | ((u32)f2bf(b) << 16);
}

// ---------- async global->LDS, 16B per lane (dest = wave-uniform base + lane*16)
__device__ __forceinline__ void gl2lds16(const u16* g, u16* l) {
  __builtin_amdgcn_global_load_lds(
      (const __attribute__((address_space(1))) void*)g,
      (__attribute__((address_space(3))) void*)l, 16, 0, 0);
}

// ---------- BK=64 twin-tile NT GEMM core (R5-proven on pv) ----------
// C(128x128) = A[MxK] * B[NxK]^T; two 128x32 sub-tiles per K-step -> half the
// barrier/drain exposures. 32 MFMAs per iteration. LDS 32KB (static).
// acc[i][j][r]: row m = wm + i*16 + (lane>>4)*4 + r ; col n = wn + j*16 + (lane&15)
#define BK 32
__device__ __forceinline__ void gemm_tile_bk64(const u16* __restrict__ A,
                                               const u16* __restrict__ B,
                                               int K, f32x4 acc[4][4]) {
  __shared__ u16 As[2][128 * 32];
  __shared__ u16 Bs[2][128 * 32];
  const int tid  = threadIdx.x;
  const int lane = tid & 63;
  const int wave = tid >> 6;
  const int wm = (wave >> 1) * 64;
  const int wn = (wave & 1) * 64;
  const int qd  = lane >> 4;
  const int l15 = lane & 15;

#pragma unroll
  for (int i = 0; i < 4; ++i)
#pragma unroll
    for (int j = 0; j < 4; ++j)
      acc[i][j] = (f32x4){0.f, 0.f, 0.f, 0.f};

  const int r0 = wave * 16 + (lane >> 2);
  const int c0 = (lane & 3) * 8;
  const u16* pa0 = A + (size_t)r0 * K + c0;
  const u16* pb0 = B + (size_t)r0 * K + c0;
  const u16* pa1 = pa0 + (size_t)64 * K;
  const u16* pb1 = pb0 + (size_t)64 * K;
  const int lo0 = wave * 512;
  const int lo1 = (4 + wave) * 512;

  for (int k0 = 0; k0 < K; k0 += 64) {
    gl2lds16(pa0,      &As[0][lo0]);
    gl2lds16(pa1,      &As[0][lo1]);
    gl2lds16(pb0,      &Bs[0][lo0]);
    gl2lds16(pb1,      &Bs[0][lo1]);
    gl2lds16(pa0 + 32, &As[1][lo0]);
    gl2lds16(pa1 + 32, &As[1][lo1]);
    gl2lds16(pb0 + 32, &Bs[1][lo0]);
    gl2lds16(pb1 + 32, &Bs[1][lo1]);
    pa0 += 64; pa1 += 64; pb0 += 64; pb1 += 64;
    __syncthreads();
#pragma unroll
    for (int h = 0; h < 2; ++h) {
      short8 af[4], bfr[4];
#pragma unroll
      for (int i = 0; i < 4; ++i)
        af[i] = *(const short8*)&As[h][(wm + i * 16 + l15) * 32 + qd * 8];
#pragma unroll
      for (int j = 0; j < 4; ++j)
        bfr[j] = *(const short8*)&Bs[h][(wn + j * 16 + l15) * 32 + qd * 8];
#pragma unroll
      for (int i = 0; i < 4; ++i)
#pragma unroll
        for (int j = 0; j < 4; ++j)
          acc[i][j] = __builtin_amdgcn_mfma_f32_16x16x32_bf16(af[i], bfr[j], acc[i][j], 0, 0, 0);
    }
    __syncthreads();
  }
}

// ---------- BK=64 twin-tile core with caller-provided LDS (32KB) ----------
// Layout in sh (u16): As0 = sh, As1 = sh+4096, Bs0 = sh+8192, Bs1 = sh+12288.
__device__ __forceinline__ void gemm_tile_bk64_sh(const u16* __restrict__ A,
                                                  const u16* __restrict__ B,
                                                  int K, f32x4 acc[4][4],
                                                  u16* sh) {
  const int tid  = threadIdx.x;
  const int lane = tid & 63;
  const int wave = tid >> 6;
  const int wm = (wave >> 1) * 64;
  const int wn = (wave & 1) * 64;
  const int qd  = lane >> 4;
  const int l15 = lane & 15;

#pragma unroll
  for (int i = 0; i < 4; ++i)
#pragma unroll
    for (int j = 0; j < 4; ++j)
      acc[i][j] = (f32x4){0.f, 0.f, 0.f, 0.f};

  const int r0 = wave * 16 + (lane >> 2);
  const int c0 = (lane & 3) * 8;
  const u16* pa0 = A + (size_t)r0 * K + c0;
  const u16* pb0 = B + (size_t)r0 * K + c0;
  const u16* pa1 = pa0 + (size_t)64 * K;
  const u16* pb1 = pb0 + (size_t)64 * K;
  const int lo0 = wave * 512;
  const int lo1 = (4 + wave) * 512;
  u16* As0 = sh;
  u16* As1 = sh + 4096;
  u16* Bs0 = sh + 8192;
  u16* Bs1 = sh + 12288;

  for (int k0 = 0; k0 < K; k0 += 64) {
    gl2lds16(pa0,      As0 + lo0);
    gl2lds16(pa1,      As0 + lo1);
    gl2lds16(pb0,      Bs0 + lo0);
    gl2lds16(pb1,      Bs0 + lo1);
    gl2lds16(pa0 + 32, As1 + lo0);
    gl2lds16(pa1 + 32, As1 + lo1);
    gl2lds16(pb0 + 32, Bs1 + lo0);
    gl2lds16(pb1 + 32, Bs1 + lo1);
    pa0 += 64; pa1 += 64; pb0 += 64; pb1 += 64;
    __syncthreads();
#pragma unroll
    for (int h = 0; h < 2; ++h) {
      const u16* Ah = h ? As1 : As0;
      const u16* Bh = h ? Bs1 : Bs0;
      short8 af[4], bfr[4];
#pragma unroll
      for (int i = 0; i < 4; ++i)
        af[i] = *(const short8*)&Ah[(wm + i * 16 + l15) * 32 + qd * 8];
#pragma unroll
      for (int j = 0; j < 4; ++j)
        bfr[j] = *(const short8*)&Bh[(wn + j * 16 + l15) * 32 + qd * 8];
#pragma unroll
      for (int i = 0; i < 4; ++i)
#pragma unroll
        for (int j = 0; j < 4; ++j)
          acc[i][j] = __builtin_amdgcn_mfma_f32_16x16x32_bf16(af[i], bfr[j], acc[i][j], 0, 0, 0);
    }
    __syncthreads();
  }
}

// ---------- converts ----------
__global__ void __launch_bounds__(256) cvt_kernel(const float* __restrict__ in,
                                                  u16* __restrict__ out, int n8) {
  int i = blockIdx.x * 256 + threadIdx.x;
  if (i >= n8) return;
  const float4* f = (const float4*)in + (size_t)i * 2;
  float4 f0 = f[0], f1 = f[1];
  uint4 u;
  u.x = pack2(f0.x, f0.y); u.y = pack2(f0.z, f0.w);
  u.z = pack2(f1.x, f1.y); u.w = pack2(f1.z, f1.w);
  *(uint4*)(out + (size_t)i * 8) = u;
}

struct CvtWArgs { const float* w[8]; };
__global__ void __launch_bounds__(256) cvt_w_kernel(CvtWArgs a, u16* __restrict__ out) {
  const int z = blockIdx.z;
  const int i = blockIdx.x * 256 + threadIdx.x;
  const float4* f = (const float4*)(a.w[z]) + (size_t)i * 2;
  float4 f0 = f[0], f1 = f[1];
  uint4 u;
  u.x = pack2(f0.x, f0.y); u.y = pack2(f0.z, f0.w);
  u.z = pack2(f1.x, f1.y); u.w = pack2(f1.z, f1.w);
  *(uint4*)(out + (size_t)z * 262144 + (size_t)i * 8) = u;
}

// ---------- zero RS ----------
__global__ void __launch_bounds__(256) zero_kernel(float* __restrict__ p, int n4) {
  int i = blockIdx.x * 256 + threadIdx.x;
  if (i < n4) ((float4*)p)[i] = (float4){0.f, 0.f, 0.f, 0.f};
}

// ---------- projections: q,k,g: out = X W^T + b (bf16). v: out = (X Wv^T + b)^T ----
// wg remap for L2 temporal locality: wg = g*32 + n*8 + b3, base = g*8+b3,
// m = base>>2, idx = base&3. X-panel n-sharers: same XCD (wg%8=b3 const) AND
// within a 32-wg window (8 apart) -> panel stays hot in the 4MB XCD-L2.
struct ProjArgs {
  const u16* X[4];
  const u16* W[4];
  const float* bias[4];
  u16* out[4];
};
__global__ void __launch_bounds__(256) proj_kernel(ProjArgs args) {
  const u32 wg = blockIdx.x;
  const int b3 = wg & 7;
  const int n  = (wg >> 3) & 3;     // 0..3
  const int g  = wg >> 5;           // 0..63
  const int base = g * 8 + b3;      // 0..511
  const int m = base >> 2;          // 0..127
  const int idx = base & 3;         // 0..3 (q,k,v,g)
  f32x4 acc[4][4];
  const u16* Aop = (idx == 2) ? args.W[2] + (size_t)(n * 128) * 512
                              : args.X[idx] + (size_t)(m * 128) * 512;
  const u16* Bop = (idx == 2) ? args.X[2] + (size_t)(m * 128) * 512
                              : args.W[idx] + (size_t)(n * 128) * 512;
  gemm_tile_bk64(Aop, Bop, 512, acc);
  const int lane = threadIdx.x & 63, wave = threadIdx.x >> 6;
  const int wm = (wave >> 1) * 64, wn = (wave & 1) * 64;
  const int qd = lane >> 4, l15 = lane & 15;
  const float* bias = args.bias[idx];
  u16* outp = args.out[idx];
  if (idx == 2) {
    // rows = d in [0,512), cols = k in [0,16384); Vt[b][d][kc], b=k>>11, kc=k&2047
    const int dRow0 = n * 128;
    const int kCol0 = m * 128;
#pragma unroll
    for (int j = 0; j < 4; ++j) {
      const int gk = kCol0 + wn + j * 16 + l15;
      const int bb = gk >> 11, kc = gk & 2047;
      u16* dcol = outp + (size_t)bb * (512 * 2048) + kc;
#pragma unroll
      for (int i = 0; i < 4; ++i) {
        const int gd0 = dRow0 + wm + i * 16 + qd * 4;
#pragma unroll
        for (int r = 0; r < 4; ++r)
          dcol[(size_t)(gd0 + r) * 2048] = f2bf(acc[i][j][r] + bias[gd0 + r]);
      }
    }
  } else {
    const int tileN = n * 128;
    const int tileM = m * 128;
#pragma unroll
    for (int j = 0; j < 4; ++j) {
      const int gn = tileN + wn + j * 16 + l15;
      const float bj = bias[gn];
#pragma unroll
      for (int i = 0; i < 4; ++i) {
        const int gm = tileM + wm + i * 16 + qd * 4;
#pragma unroll
        for (int r = 0; r < 4; ++r)
          outp[(size_t)(gm + r) * 512 + gn] = f2bf(acc[i][j][r] + bj);
      }
    }
  }
}

// ---------- P' = exp(scale * Q K^T) (8 batches), bf16 out, no max-subtract ----
// BK=64 core (8 K-iterations) + LDS-staged vectorized store epilogue (R6).
__global__ void __launch_bounds__(256) qk_kernel(const u16* __restrict__ Q,
                                                 const u16* __restrict__ Kmat,
                                                 u16* __restrict__ S,
                                                 float* __restrict__ RS) {
  __shared__ u16 sh[16384];                // 32KB: GEMM staging, then f32 C-scratch
  const u32 wg = blockIdx.x;
  const int n = wg >> 7;            // 0..15
  const int m = (wg >> 3) & 15;     // 0..15
  const int b = wg & 7;             // 0..7
  const int tileN = n * 128;
  const int tileM = m * 128;
  f32x4 acc[4][4];
  gemm_tile_bk64_sh(Q + (size_t)b * 2048 * 512 + (size_t)tileM * 512,
                    Kmat + (size_t)b * 2048 * 512 + (size_t)tileN * 512, 512, acc,
                    sh);
  const int tid = threadIdx.x;
  const int lane = tid & 63, wave = tid >> 6;
  const int wm = (wave >> 1) * 64, wn = (wave & 1) * 64;
  const int qd = lane >> 4, l15 = lane & 15;
  u16* Sp = S + (size_t)b * 2048 * 2048;
  float* RSb = RS + (size_t)b * 2048;
  const float scale = 0.04419417382415922f;  // 1/sqrt(512)
  float* scr = (float*)sh;                   // 4096 f32 = 32 rows x 128 cols (16KB)

#pragma unroll
  for (int p = 0; p < 4; ++p) {
    // scatter this pass's 32 rows (global rows tileM+32p .. +31) into scratch
    if ((wm >> 6) == (p >> 1)) {
#pragma unroll
      for (int ii = 0; ii < 2; ++ii) {
        const int i = 2 * (p & 1) + ii;
#pragma unroll
        for (int j = 0; j < 4; ++j) {
          const int col = wn + j * 16 + l15;
#pragma unroll
          for (int r = 0; r < 4; ++r)
            scr[(ii * 16 + qd * 4 + r) * 128 + col] = acc[i][j][r];
        }
      }
    }
    __syncthreads();
    // contiguous readback: 16 f32/thread -> exp -> 16 bf16 -> 2 x uint4 store
    const float4* sp = (const float4*)(scr + (size_t)tid * 16);
    float e[16];
#pragma unroll
    for (int k = 0; k < 4; ++k) {
      float4 v = sp[k];
      e[k * 4 + 0] = __expf(v.x * scale);
      e[k * 4 + 1] = __expf(v.y * scale);
      e[k * 4 + 2] = __expf(v.z * scale);
      e[k * 4 + 3] = __expf(v.w * scale);
    }
    const int grow = tileM + 32 * p + (tid >> 3);
    const int gcol = tileN + (tid & 7) * 16;
    uint4 s0, s1;
    s0.x = pack2(e[0], e[1]);  s0.y = pack2(e[2], e[3]);
    s0.z = pack2(e[4], e[5]);  s0.w = pack2(e[6], e[7]);
    s1.x = pack2(e[8], e[9]);  s1.y = pack2(e[10], e[11]);
    s1.z = pack2(e[12], e[13]); s1.w = pack2(e[14], e[15]);
    u16* dst = Sp + (size_t)grow * 2048 + gcol;
    *(uint4*)dst = s0;
    *(uint4*)(dst + 8) = s1;
    float rs = 0.f;
#pragma unroll
    for (int k = 0; k < 16; ++k) rs += e[k];
    rs += __shfl_xor(rs, 1);
    rs += __shfl_xor(rs, 2);
    rs += __shfl_xor(rs, 4);
    if ((tid & 7) == 0) atomicAdd(&RSb[grow], rs);
    __syncthreads();   // scratch reused next pass
  }
}

// ---------- O = P' V ; out = hq + sigmoid(g) * O / RS[row] ----------
// 128x128 tiles, BK=64 twin-tile core: 32 barrier/drain exposures instead of 64.
__global__ void __launch_bounds__(256) pv_kernel(const u16* __restrict__ P,
                                                 const u16* __restrict__ Vt,
                                                 const float* __restrict__ hq,
                                                 const u16* __restrict__ gate,
                                                 const float* __restrict__ RS,
                                                 float* __restrict__ outp) {
  const u32 wg = blockIdx.x;
  const int n = wg >> 7;            // 0..3
  const int m = (wg >> 3) & 15;     // 0..15
  const int b = wg & 7;             // 0..7
  const int tileN = n * 128;
  const int tileM = m * 128;
  f32x4 acc[4][4];
  gemm_tile_bk64(P + (size_t)b * 2048 * 2048 + (size_t)tileM * 2048,
                 Vt + (size_t)b * 512 * 2048 + (size_t)tileN * 2048, 2048, acc);
  const int lane = threadIdx.x & 63, wave = threadIdx.x >> 6;
  const int wm = (wave >> 1) * 64, wn = (wave & 1) * 64;
  const int qd = lane >> 4, l15 = lane & 15;
  float invr[4][4];
#pragma unroll
  for (int i = 0; i < 4; ++i) {
    const int lm = wm + i * 16 + qd * 4;
#pragma unroll
    for (int r = 0; r < 4; ++r)
      invr[i][r] = 1.f / RS[(size_t)b * 2048 + tileM + lm + r];
  }
#pragma unroll
  for (int j = 0; j < 4; ++j) {
    const int gn = tileN + wn + j * 16 + l15;
#pragma unroll
    for (int i = 0; i < 4; ++i) {
      const int lm = wm + i * 16 + qd * 4;
#pragma unroll
      for (int r = 0; r < 4; ++r) {
        const size_t o = (size_t)(b * 2048 + tileM + lm + r) * 512 + gn;
        const float gv = bf2f(gate[o]);
        outp[o] = hq[o] + (acc[i][j][r] * invr[i][r]) / (1.f + __expf(-gv));
      }
    }
  }
}

extern "C" void kernel_launch(void* const* d_in, const int* in_sizes, int n_in,
                              void* d_out, int out_size, void* d_ws, size_t ws_size,
                              hipStream_t stream) {
  const size_t NX = (size_t)16384 * 512;   // per-direction tensor elems (B*L*D)
  // ws layout (u16 elems): ~172 MB total
  u16* Xb = (u16*)d_ws;                    // [2][16384][512] bf16 h_s, h_c
  u16* Wb = Xb + 2 * NX;                   // [8][512][512]
  u16* Qd = Wb + (size_t)8 * 262144;       // per-dir [8][2048][512]
  u16* Kd = Qd + NX;
  u16* Vt = Kd + NX;                       // per-dir [8][512][2048] (direct-transposed V)
  u16* Gd = Vt + NX;
  u16* Sd = Gd + NX;                       // per-dir [8][2048][2048] (P' = exp)
  float* RS = (float*)(Sd + 4 * NX);       // [2][8][2048] f32 rowsums

  // converts (once)
  cvt_kernel<<<dim3((u32)(NX / 2048)), 256, 0, stream>>>((const float*)d_in[0], Xb, (int)(NX / 8));
  cvt_kernel<<<dim3((u32)(NX / 2048)), 256, 0, stream>>>((const float*)d_in[1], Xb + NX, (int)(NX / 8));
  // Wb slot order: qs,kc,vc,gs | qc,ks,vs,gc
  static const int wsrc[8] = {2, 4, 6, 14, 8, 10, 12, 16};
  CvtWArgs wa;
  for (int i = 0; i < 8; ++i) wa.w[i] = (const float*)d_in[wsrc[i]];
  cvt_w_kernel<<<dim3(128, 1, 8), 256, 0, stream>>>(wa, Wb);
  zero_kernel<<<dim3(32), 256, 0, stream>>>(RS, 8192);   // 2*8*2048 f32 = 8192 float4

  for (int dir = 0; dir < 2; ++dir) {
    const u16* Xq  = dir ? Xb + NX : Xb;   // h_q source (h_s for dir0, h_c for dir1)
    const u16* Xkv = dir ? Xb : Xb + NX;
    static const int wslot[2][4] = {{0, 1, 2, 3}, {4, 5, 6, 7}};
    static const int bidx[2][4]  = {{3, 5, 7, 15}, {9, 11, 13, 17}};
    const u16* xin[4] = {Xq, Xkv, Xkv, Xq};
    u16* outs[4] = {Qd, Kd, Vt, Gd};
    ProjArgs pa;
    for (int i = 0; i < 4; ++i) {
      pa.X[i] = xin[i];
      pa.W[i] = Wb + (size_t)262144 * wslot[dir][i];
      pa.bias[i] = (const float*)d_in[bidx[dir][i]];
      pa.out[i] = outs[i];
    }
    proj_kernel<<<dim3(2048), 256, 0, stream>>>(pa);

    float* RSd = RS + (size_t)dir * 16384;
    qk_kernel<<<dim3(2048), 256, 0, stream>>>(Qd, Kd, Sd, RSd);
    pv_kernel<<<dim3(512), 256, 0, stream>>>(
        Sd, Vt, (const float*)d_in[dir], Gd, RSd, (float*)d_out + dir * NX);
  }
}